// Round 1
// baseline (683.697 us; speedup 1.0000x reference)
//
#include <hip/hip_runtime.h>

#define V_ 50000
#define E_ 300000
#define B_ 4
#define LAT_ 512
#define H_ 128
#define L_ 3
#define N_ (B_*V_)

// ---------------------------------------------------------------------------
// Graph preprocessing
// ---------------------------------------------------------------------------

__global__ void k_zero(int* __restrict__ deg, int* __restrict__ cursor) {
    int i = blockIdx.x * 256 + threadIdx.x;
    if (i < V_) { deg[i] = 0; cursor[i] = 0; }
}

__global__ void k_deg(const int* __restrict__ dst, int* __restrict__ deg) {
    int e = blockIdx.x * 256 + threadIdx.x;
    if (e < E_) atomicAdd(&deg[dst[e]], 1);
}

// Single-block scan over V: offsets (exclusive prefix of indeg) + dis = rsqrt(B*indeg+1)
__global__ __launch_bounds__(1024) void k_scan(const int* __restrict__ deg,
                                               int* __restrict__ off,
                                               float* __restrict__ dis) {
    const int T = 1024;
    const int C = (V_ + T - 1) / T;   // 49
    int t = threadIdx.x;
    int lo = t * C;
    int hi = lo + C; if (hi > V_) hi = V_;
    int s = 0;
    for (int i = lo; i < hi; i++) s += deg[i];
    __shared__ int sums[T];
    sums[t] = s;
    __syncthreads();
    int val = s;
    for (int d = 1; d < T; d <<= 1) {
        int other = (t >= d) ? sums[t - d] : 0;
        __syncthreads();
        val += other;
        sums[t] = val;
        __syncthreads();
    }
    int running = val - s;            // exclusive prefix
    for (int i = lo; i < hi; i++) {
        off[i] = running;
        running += deg[i];
        dis[i] = rsqrtf((float)(B_ * deg[i] + 1));
    }
    if (hi == V_) off[V_] = running;  // == E_ (threads past the end also write E_)
}

__global__ void k_fill(const int* __restrict__ src, const int* __restrict__ dst,
                       const int* __restrict__ off, int* __restrict__ cursor,
                       int* __restrict__ csr) {
    int e = blockIdx.x * 256 + threadIdx.x;
    if (e < E_) {
        int c = dst[e];
        int p = atomicAdd(&cursor[c], 1);
        csr[off[c] + p] = src[e];
    }
}

// ---------------------------------------------------------------------------
// Input projection: latproj[b][j] = b_in[j] + sum_k W_in[j][3+k] * latent[b][k]
// ---------------------------------------------------------------------------

__global__ void k_latproj(const float* __restrict__ Win, const float* __restrict__ bin,
                          const float* __restrict__ latent, float* __restrict__ latproj) {
    int t = blockIdx.x * 128 + threadIdx.x;   // 512 threads total
    if (t >= B_ * H_) return;
    int b = t >> 7, j = t & 127;
    const float* wr = Win + (size_t)j * (LAT_ + 3) + 3;
    const float* lp = latent + (size_t)b * LAT_;
    float s = bin[j];
    for (int k = 0; k < LAT_; k++) s = fmaf(wr[k], lp[k], s);
    latproj[t] = s;
}

// x0[node][j] = relu(W_in[j][0..2] . xyz[v] + latproj[b][j])
__global__ void k_x0(const float* __restrict__ xyz, const float* __restrict__ Win,
                     const float* __restrict__ latproj, float* __restrict__ x) {
    size_t idx = (size_t)blockIdx.x * 256 + threadIdx.x;   // over N_*H_
    int j = (int)(idx & 127);
    size_t node = idx >> 7;
    int v = (int)(node % V_);
    int b = (int)(node / V_);
    const float* wr = Win + (size_t)j * (LAT_ + 3);
    float s = latproj[b * H_ + j];
    s = fmaf(wr[0], xyz[v * 3 + 0], s);
    s = fmaf(wr[1], xyz[v * 3 + 1], s);
    s = fmaf(wr[2], xyz[v * 3 + 2], s);
    x[idx] = fmaxf(s, 0.f);
}

// ---------------------------------------------------------------------------
// Conv GEMM: h = x @ W^T  (N_ x 128 @ 128 x 128), f32 vector, register-tiled
// block = 256 threads, 64 rows x 128 cols per block
// ---------------------------------------------------------------------------

__global__ __launch_bounds__(256) void k_gemm(const float* __restrict__ x,
                                              const float* __restrict__ W,
                                              float* __restrict__ h) {
    __shared__ float xs[64][36];    // row-major chunk, stride 36 floats (16B-aligned rows)
    __shared__ float ws[32][128];   // k-major: ws[kk][c]
    const int tid = threadIdx.x;
    const int row0 = blockIdx.x * 64;
    const int cg = tid & 31;        // 32 col groups of 4
    const int rg = tid >> 5;        // 8 row groups of 8
    float acc[8][4];
#pragma unroll
    for (int i = 0; i < 8; i++)
#pragma unroll
        for (int j = 0; j < 4; j++) acc[i][j] = 0.f;

    for (int k0 = 0; k0 < 128; k0 += 32) {
        __syncthreads();
        {   // load x chunk: 64 rows x 32 k
            int r  = tid >> 2;            // 0..63
            int kk = (tid & 3) * 8;       // 0,8,16,24
            const float* src = x + (size_t)(row0 + r) * 128 + k0 + kk;
            float4 a = *(const float4*)(src);
            float4 b = *(const float4*)(src + 4);
            *(float4*)&xs[r][kk]     = a;
            *(float4*)&xs[r][kk + 4] = b;
        }
        {   // load W chunk transposed: ws[kk][c] = W[c*128 + k0+kk]
            int c  = tid >> 1;            // 0..127
            int kk = (tid & 1) * 16;      // 0 or 16
            const float* src = W + (size_t)c * 128 + k0 + kk;
#pragma unroll
            for (int q = 0; q < 16; q += 4) {
                float4 a = *(const float4*)(src + q);
                ws[kk + q + 0][c] = a.x;
                ws[kk + q + 1][c] = a.y;
                ws[kk + q + 2][c] = a.z;
                ws[kk + q + 3][c] = a.w;
            }
        }
        __syncthreads();
#pragma unroll
        for (int kk = 0; kk < 32; kk++) {
            float4 w4 = *(const float4*)&ws[kk][cg * 4];
            float xr[8];
#pragma unroll
            for (int i = 0; i < 8; i++) xr[i] = xs[rg * 8 + i][kk];
#pragma unroll
            for (int i = 0; i < 8; i++) {
                acc[i][0] = fmaf(xr[i], w4.x, acc[i][0]);
                acc[i][1] = fmaf(xr[i], w4.y, acc[i][1]);
                acc[i][2] = fmaf(xr[i], w4.z, acc[i][2]);
                acc[i][3] = fmaf(xr[i], w4.w, acc[i][3]);
            }
        }
    }
#pragma unroll
    for (int i = 0; i < 8; i++) {
        float4 v = make_float4(acc[i][0], acc[i][1], acc[i][2], acc[i][3]);
        *(float4*)(h + (size_t)(row0 + rg * 8 + i) * 128 + cg * 4) = v;
    }
}

// ---------------------------------------------------------------------------
// Aggregation + bias + relu. One wave per node.
// c <  V_: x[c] = relu(dis_c*B*sum_i dis_u * h[u_i] + dis_c^2 * h[c] + b)
// c >= V_: x[c] = relu(h[c] + b)                        (self-loop only, norm=1)
// ---------------------------------------------------------------------------

__global__ __launch_bounds__(256) void k_agg(const float* __restrict__ h,
                                             const float* __restrict__ dis,
                                             const int* __restrict__ off,
                                             const int* __restrict__ csr,
                                             const float* __restrict__ bias,
                                             float* __restrict__ xout) {
    int c = (int)(((size_t)blockIdx.x * 256 + threadIdx.x) >> 6);
    int lane = threadIdx.x & 63;
    if (c >= N_) return;
    const float* hr = h + (size_t)c * 128;
    float b0 = bias[lane], b1 = bias[lane + 64];
    if (c < V_) {
        float dc = dis[c];
        float a0 = 0.f, a1 = 0.f;
        int beg = off[c], end = off[c + 1];
        for (int i = beg; i < end; i++) {
            int u = csr[i];
            float wu = dis[u];
            const float* hu = h + (size_t)u * 128;
            a0 = fmaf(wu, hu[lane],      a0);
            a1 = fmaf(wu, hu[lane + 64], a1);
        }
        float s0 = dc * (float)B_ * a0 + dc * dc * hr[lane]      + b0;
        float s1 = dc * (float)B_ * a1 + dc * dc * hr[lane + 64] + b1;
        xout[(size_t)c * 128 + lane]      = fmaxf(s0, 0.f);
        xout[(size_t)c * 128 + lane + 64] = fmaxf(s1, 0.f);
    } else {
        xout[(size_t)c * 128 + lane]      = fmaxf(hr[lane]      + b0, 0.f);
        xout[(size_t)c * 128 + lane + 64] = fmaxf(hr[lane + 64] + b1, 0.f);
    }
}

// ---------------------------------------------------------------------------
// Output head: out[n][o] = x[n] . W_out[o] + b_out[o].  One wave per node.
// ---------------------------------------------------------------------------

__global__ __launch_bounds__(256) void k_out(const float* __restrict__ x,
                                             const float* __restrict__ Wout,
                                             const float* __restrict__ bout,
                                             float* __restrict__ out) {
    int n = (int)(((size_t)blockIdx.x * 256 + threadIdx.x) >> 6);
    int lane = threadIdx.x & 63;
    if (n >= N_) return;
    float x0 = x[(size_t)n * 128 + lane];
    float x1 = x[(size_t)n * 128 + 64 + lane];
#pragma unroll
    for (int o = 0; o < 3; o++) {
        float a = x0 * Wout[o * 128 + lane] + x1 * Wout[o * 128 + 64 + lane];
#pragma unroll
        for (int d = 32; d; d >>= 1) a += __shfl_down(a, d);
        if (lane == 0) out[(size_t)n * 3 + o] = a + bout[o];
    }
}

// ---------------------------------------------------------------------------

extern "C" void kernel_launch(void* const* d_in, const int* in_sizes, int n_in,
                              void* d_out, int out_size, void* d_ws, size_t ws_size,
                              hipStream_t stream) {
    const float* xyz    = (const float*)d_in[0];
    const float* latent = (const float*)d_in[1];
    const int*   ei     = (const int*)d_in[2];      // [2][E_]: row 0 = src, row 1 = dst
    const float* Win    = (const float*)d_in[3];    // [H_][LAT_+3]
    const float* bin    = (const float*)d_in[4];
    const float* convW  = (const float*)d_in[5];    // [L_][H_][H_]
    const float* convb  = (const float*)d_in[6];    // [L_][H_]
    const float* Wout   = (const float*)d_in[7];    // [3][H_]
    const float* bout   = (const float*)d_in[8];
    float* out = (float*)d_out;

    // workspace carve (256B aligned)
    char* w = (char*)d_ws;
    auto carve = [&](size_t bytes) {
        char* p = w;
        w += (bytes + 255) & ~(size_t)255;
        return p;
    };
    float* x       = (float*)carve((size_t)N_ * H_ * 4);
    float* h       = (float*)carve((size_t)N_ * H_ * 4);
    float* dis     = (float*)carve((size_t)V_ * 4);
    float* latproj = (float*)carve((size_t)B_ * H_ * 4);
    int*   deg     = (int*)carve((size_t)V_ * 4);
    int*   off     = (int*)carve((size_t)(V_ + 1) * 4);
    int*   cursor  = (int*)carve((size_t)V_ * 4);
    int*   csr     = (int*)carve((size_t)E_ * 4);
    (void)ws_size; (void)in_sizes; (void)n_in; (void)out_size;

    const int* src = ei;
    const int* dst = ei + E_;

    k_zero<<<(V_ + 255) / 256, 256, 0, stream>>>(deg, cursor);
    k_deg<<<(E_ + 255) / 256, 256, 0, stream>>>(dst, deg);
    k_scan<<<1, 1024, 0, stream>>>(deg, off, dis);
    k_fill<<<(E_ + 255) / 256, 256, 0, stream>>>(src, dst, off, cursor, csr);

    k_latproj<<<4, 128, 0, stream>>>(Win, bin, latent, latproj);
    k_x0<<<(int)(((size_t)N_ * H_) / 256), 256, 0, stream>>>(xyz, Win, latproj, x);

    for (int l = 0; l < L_; l++) {
        k_gemm<<<N_ / 64, 256, 0, stream>>>(x, convW + (size_t)l * H_ * H_, h);
        k_agg<<<N_ / 4, 256, 0, stream>>>(h, dis, off, csr, convb + (size_t)l * H_, x);
    }

    k_out<<<N_ / 4, 256, 0, stream>>>(x, Wout, bout, out);
}

// Round 2
// 584.192 us; speedup vs baseline: 1.1703x; 1.1703x over previous
//
#include <hip/hip_runtime.h>

#define V_ 50000
#define E_ 300000
#define B_ 4
#define LAT_ 512
#define H_ 128
#define L_ 3
#define N_ (B_*V_)

#define SCAN_B 512
#define SCAN_G ((V_ + SCAN_B - 1) / SCAN_B)   // 98

// ---------------------------------------------------------------------------
// Graph preprocessing
// ---------------------------------------------------------------------------

__global__ void k_zero(int* __restrict__ deg, int* __restrict__ cursor) {
    int i = blockIdx.x * 256 + threadIdx.x;
    if (i < V_) { deg[i] = 0; cursor[i] = 0; }
}

__global__ void k_deg(const int* __restrict__ dst, int* __restrict__ deg) {
    int e = blockIdx.x * 256 + threadIdx.x;
    if (e < E_) atomicAdd(&deg[dst[e]], 1);
}

// Stage 1: per-block exclusive scan of deg; write dis; write block sums.
__global__ __launch_bounds__(SCAN_B) void k_scan1(const int* __restrict__ deg,
                                                  int* __restrict__ off,
                                                  float* __restrict__ dis,
                                                  int* __restrict__ part) {
    int t = threadIdx.x;
    int i = blockIdx.x * SCAN_B + t;
    int d = (i < V_) ? deg[i] : 0;
    __shared__ int sm[SCAN_B];
    sm[t] = d;
    __syncthreads();
    int val = d;
    for (int s = 1; s < SCAN_B; s <<= 1) {
        int o = (t >= s) ? sm[t - s] : 0;
        __syncthreads();
        val += o;
        sm[t] = val;
        __syncthreads();
    }
    if (i < V_) {
        off[i] = val - d;                         // exclusive within block
        dis[i] = rsqrtf((float)(B_ * d + 1));
    }
    if (t == SCAN_B - 1) part[blockIdx.x] = val;  // block total
}

// Stage 2: exclusive scan of the 98 block totals (one small block).
__global__ void k_scan2(int* __restrict__ part) {
    __shared__ int sm[128];
    int t = threadIdx.x;
    int v = (t < SCAN_G) ? part[t] : 0;
    sm[t] = v;
    __syncthreads();
    int val = v;
    for (int s = 1; s < 128; s <<= 1) {
        int o = (t >= s) ? sm[t - s] : 0;
        __syncthreads();
        val += o;
        sm[t] = val;
        __syncthreads();
    }
    if (t < SCAN_G) part[t] = val - v;            // exclusive
}

// Stage 3: add block base; fix up off[V].
__global__ __launch_bounds__(SCAN_B) void k_scan3(int* __restrict__ off,
                                                  const int* __restrict__ part) {
    int i = blockIdx.x * SCAN_B + threadIdx.x;
    if (i < V_) off[i] += part[blockIdx.x];
    if (i == 0) off[V_] = E_;                     // total in-degree == E
}

__global__ void k_fill(const int* __restrict__ src, const int* __restrict__ dst,
                       const int* __restrict__ off, int* __restrict__ cursor,
                       int* __restrict__ csr) {
    int e = blockIdx.x * 256 + threadIdx.x;
    if (e < E_) {
        int c = dst[e];
        int p = atomicAdd(&cursor[c], 1);
        csr[off[c] + p] = src[e];
    }
}

// ---------------------------------------------------------------------------
// Input projection: latproj[b][j] = b_in[j] + sum_k W_in[j][3+k] * latent[b][k]
// ---------------------------------------------------------------------------

__global__ void k_latproj(const float* __restrict__ Win, const float* __restrict__ bin,
                          const float* __restrict__ latent, float* __restrict__ latproj) {
    int t = blockIdx.x * 128 + threadIdx.x;   // 512 threads total
    if (t >= B_ * H_) return;
    int b = t >> 7, j = t & 127;
    const float* wr = Win + (size_t)j * (LAT_ + 3) + 3;
    const float* lp = latent + (size_t)b * LAT_;
    float s = bin[j];
    for (int k = 0; k < LAT_; k++) s = fmaf(wr[k], lp[k], s);
    latproj[t] = s;
}

// x0[node][j] = relu(W_in[j][0..2] . xyz[v] + latproj[b][j])
__global__ void k_x0(const float* __restrict__ xyz, const float* __restrict__ Win,
                     const float* __restrict__ latproj, float* __restrict__ x) {
    size_t idx = (size_t)blockIdx.x * 256 + threadIdx.x;   // over N_*H_
    int j = (int)(idx & 127);
    size_t node = idx >> 7;
    int v = (int)(node % V_);
    int b = (int)(node / V_);
    const float* wr = Win + (size_t)j * (LAT_ + 3);
    float s = latproj[b * H_ + j];
    s = fmaf(wr[0], xyz[v * 3 + 0], s);
    s = fmaf(wr[1], xyz[v * 3 + 1], s);
    s = fmaf(wr[2], xyz[v * 3 + 2], s);
    x[idx] = fmaxf(s, 0.f);
}

// ---------------------------------------------------------------------------
// Conv GEMM: h = x @ W^T  (N_ x 128 @ 128 x 128), f32 vector, register-tiled
// block = 256 threads, 64 rows x 128 cols per block.
// Inner loop fully float4: per 4-kk chunk per wave = 12 ds_read_b128 (~144 cyc)
// vs 256 cyc of FMA -> VALU-bound.
// ---------------------------------------------------------------------------

__global__ __launch_bounds__(256) void k_gemm(const float* __restrict__ x,
                                              const float* __restrict__ W,
                                              float* __restrict__ h) {
    __shared__ float xs[64][36];    // row stride 36 floats = 144 B (16B-aligned rows)
    __shared__ float ws[32][128];   // k-major: ws[kk][c]
    const int tid = threadIdx.x;
    const int row0 = blockIdx.x * 64;
    const int cg = tid & 31;        // 32 col groups of 4
    const int rg = tid >> 5;        // 8 row groups of 8
    float acc[8][4];
#pragma unroll
    for (int i = 0; i < 8; i++)
#pragma unroll
        for (int j = 0; j < 4; j++) acc[i][j] = 0.f;

    for (int k0 = 0; k0 < 128; k0 += 32) {
        __syncthreads();
        {   // load x chunk: 64 rows x 32 k
            int r  = tid >> 2;            // 0..63
            int kk = (tid & 3) * 8;       // 0,8,16,24
            const float* src = x + (size_t)(row0 + r) * 128 + k0 + kk;
            float4 a = *(const float4*)(src);
            float4 b = *(const float4*)(src + 4);
            *(float4*)&xs[r][kk]     = a;
            *(float4*)&xs[r][kk + 4] = b;
        }
        {   // load W chunk transposed: ws[kk][c] = W[c*128 + k0+kk]
            int c  = tid >> 1;            // 0..127
            int kk = (tid & 1) * 16;      // 0 or 16
            const float* src = W + (size_t)c * 128 + k0 + kk;
#pragma unroll
            for (int q = 0; q < 16; q += 4) {
                float4 a = *(const float4*)(src + q);
                ws[kk + q + 0][c] = a.x;
                ws[kk + q + 1][c] = a.y;
                ws[kk + q + 2][c] = a.z;
                ws[kk + q + 3][c] = a.w;
            }
        }
        __syncthreads();
#pragma unroll
        for (int kk = 0; kk < 32; kk += 4) {
            float4 w0 = *(const float4*)&ws[kk + 0][cg * 4];
            float4 w1 = *(const float4*)&ws[kk + 1][cg * 4];
            float4 w2 = *(const float4*)&ws[kk + 2][cg * 4];
            float4 w3 = *(const float4*)&ws[kk + 3][cg * 4];
#pragma unroll
            for (int i = 0; i < 8; i++) {
                float4 xv = *(const float4*)&xs[rg * 8 + i][kk];
                acc[i][0] = fmaf(xv.x, w0.x, acc[i][0]);
                acc[i][1] = fmaf(xv.x, w0.y, acc[i][1]);
                acc[i][2] = fmaf(xv.x, w0.z, acc[i][2]);
                acc[i][3] = fmaf(xv.x, w0.w, acc[i][3]);
                acc[i][0] = fmaf(xv.y, w1.x, acc[i][0]);
                acc[i][1] = fmaf(xv.y, w1.y, acc[i][1]);
                acc[i][2] = fmaf(xv.y, w1.z, acc[i][2]);
                acc[i][3] = fmaf(xv.y, w1.w, acc[i][3]);
                acc[i][0] = fmaf(xv.z, w2.x, acc[i][0]);
                acc[i][1] = fmaf(xv.z, w2.y, acc[i][1]);
                acc[i][2] = fmaf(xv.z, w2.z, acc[i][2]);
                acc[i][3] = fmaf(xv.z, w2.w, acc[i][3]);
                acc[i][0] = fmaf(xv.w, w3.x, acc[i][0]);
                acc[i][1] = fmaf(xv.w, w3.y, acc[i][1]);
                acc[i][2] = fmaf(xv.w, w3.z, acc[i][2]);
                acc[i][3] = fmaf(xv.w, w3.w, acc[i][3]);
            }
        }
    }
#pragma unroll
    for (int i = 0; i < 8; i++) {
        float4 v = make_float4(acc[i][0], acc[i][1], acc[i][2], acc[i][3]);
        *(float4*)(h + (size_t)(row0 + rg * 8 + i) * 128 + cg * 4) = v;
    }
}

// ---------------------------------------------------------------------------
// Aggregation + bias + relu. One wave per node.
// c <  V_: x[c] = relu(dis_c*B*sum_i dis_u * h[u_i] + dis_c^2 * h[c] + b)
// c >= V_: x[c] = relu(h[c] + b)                        (self-loop only, norm=1)
// ---------------------------------------------------------------------------

__global__ __launch_bounds__(256) void k_agg(const float* __restrict__ h,
                                             const float* __restrict__ dis,
                                             const int* __restrict__ off,
                                             const int* __restrict__ csr,
                                             const float* __restrict__ bias,
                                             float* __restrict__ xout) {
    int c = (int)(((size_t)blockIdx.x * 256 + threadIdx.x) >> 6);
    int lane = threadIdx.x & 63;
    if (c >= N_) return;
    const float* hr = h + (size_t)c * 128;
    float b0 = bias[lane], b1 = bias[lane + 64];
    if (c < V_) {
        float dc = dis[c];
        float a0 = 0.f, a1 = 0.f;
        int beg = off[c], end = off[c + 1];
        for (int i = beg; i < end; i++) {
            int u = csr[i];
            float wu = dis[u];
            const float* hu = h + (size_t)u * 128;
            a0 = fmaf(wu, hu[lane],      a0);
            a1 = fmaf(wu, hu[lane + 64], a1);
        }
        float s0 = dc * (float)B_ * a0 + dc * dc * hr[lane]      + b0;
        float s1 = dc * (float)B_ * a1 + dc * dc * hr[lane + 64] + b1;
        xout[(size_t)c * 128 + lane]      = fmaxf(s0, 0.f);
        xout[(size_t)c * 128 + lane + 64] = fmaxf(s1, 0.f);
    } else {
        xout[(size_t)c * 128 + lane]      = fmaxf(hr[lane]      + b0, 0.f);
        xout[(size_t)c * 128 + lane + 64] = fmaxf(hr[lane + 64] + b1, 0.f);
    }
}

// ---------------------------------------------------------------------------
// Output head: out[n][o] = x[n] . W_out[o] + b_out[o].  One wave per node.
// ---------------------------------------------------------------------------

__global__ __launch_bounds__(256) void k_out(const float* __restrict__ x,
                                             const float* __restrict__ Wout,
                                             const float* __restrict__ bout,
                                             float* __restrict__ out) {
    int n = (int)(((size_t)blockIdx.x * 256 + threadIdx.x) >> 6);
    int lane = threadIdx.x & 63;
    if (n >= N_) return;
    float x0 = x[(size_t)n * 128 + lane];
    float x1 = x[(size_t)n * 128 + 64 + lane];
#pragma unroll
    for (int o = 0; o < 3; o++) {
        float a = x0 * Wout[o * 128 + lane] + x1 * Wout[o * 128 + 64 + lane];
#pragma unroll
        for (int d = 32; d; d >>= 1) a += __shfl_down(a, d);
        if (lane == 0) out[(size_t)n * 3 + o] = a + bout[o];
    }
}

// ---------------------------------------------------------------------------

extern "C" void kernel_launch(void* const* d_in, const int* in_sizes, int n_in,
                              void* d_out, int out_size, void* d_ws, size_t ws_size,
                              hipStream_t stream) {
    const float* xyz    = (const float*)d_in[0];
    const float* latent = (const float*)d_in[1];
    const int*   ei     = (const int*)d_in[2];      // [2][E_]: row 0 = src, row 1 = dst
    const float* Win    = (const float*)d_in[3];    // [H_][LAT_+3]
    const float* bin    = (const float*)d_in[4];
    const float* convW  = (const float*)d_in[5];    // [L_][H_][H_]
    const float* convb  = (const float*)d_in[6];    // [L_][H_]
    const float* Wout   = (const float*)d_in[7];    // [3][H_]
    const float* bout   = (const float*)d_in[8];
    float* out = (float*)d_out;

    // workspace carve (256B aligned)
    char* w = (char*)d_ws;
    auto carve = [&](size_t bytes) {
        char* p = w;
        w += (bytes + 255) & ~(size_t)255;
        return p;
    };
    float* x       = (float*)carve((size_t)N_ * H_ * 4);
    float* h       = (float*)carve((size_t)N_ * H_ * 4);
    float* dis     = (float*)carve((size_t)V_ * 4);
    float* latproj = (float*)carve((size_t)B_ * H_ * 4);
    int*   deg     = (int*)carve((size_t)V_ * 4);
    int*   off     = (int*)carve((size_t)(V_ + 1) * 4);
    int*   cursor  = (int*)carve((size_t)V_ * 4);
    int*   csr     = (int*)carve((size_t)E_ * 4);
    int*   part    = (int*)carve((size_t)SCAN_G * 4);
    (void)ws_size; (void)in_sizes; (void)n_in; (void)out_size;

    const int* src = ei;
    const int* dst = ei + E_;

    k_zero<<<(V_ + 255) / 256, 256, 0, stream>>>(deg, cursor);
    k_deg<<<(E_ + 255) / 256, 256, 0, stream>>>(dst, deg);
    k_scan1<<<SCAN_G, SCAN_B, 0, stream>>>(deg, off, dis, part);
    k_scan2<<<1, 128, 0, stream>>>(part);
    k_scan3<<<SCAN_G, SCAN_B, 0, stream>>>(off, part);
    k_fill<<<(E_ + 255) / 256, 256, 0, stream>>>(src, dst, off, cursor, csr);

    k_latproj<<<4, 128, 0, stream>>>(Win, bin, latent, latproj);
    k_x0<<<(int)(((size_t)N_ * H_) / 256), 256, 0, stream>>>(xyz, Win, latproj, x);

    for (int l = 0; l < L_; l++) {
        k_gemm<<<N_ / 64, 256, 0, stream>>>(x, convW + (size_t)l * H_ * H_, h);
        k_agg<<<N_ / 4, 256, 0, stream>>>(h, dis, off, csr, convb + (size_t)l * H_, x);
    }

    k_out<<<N_ / 4, 256, 0, stream>>>(x, Wout, bout, out);
}

// Round 3
// 504.414 us; speedup vs baseline: 1.3554x; 1.1582x over previous
//
#include <hip/hip_runtime.h>
#include <hip/hip_bf16.h>

typedef __attribute__((ext_vector_type(8))) short short8;
typedef __attribute__((ext_vector_type(4))) float f32x4;

#define V_ 50000
#define E_ 300000
#define B_ 4
#define LAT_ 512
#define H_ 128
#define L_ 3
#define N_ (B_*V_)

#define SCAN_B 512
#define SCAN_G ((V_ + SCAN_B - 1) / SCAN_B)   // 98

// ---------------------------------------------------------------------------
// Graph preprocessing
// ---------------------------------------------------------------------------

__global__ void k_zero(int* __restrict__ deg, int* __restrict__ cursor) {
    int i = blockIdx.x * 256 + threadIdx.x;
    if (i < V_) { deg[i] = 0; cursor[i] = 0; }
}

__global__ void k_deg(const int* __restrict__ dst, int* __restrict__ deg) {
    int e = blockIdx.x * 256 + threadIdx.x;
    if (e < E_) atomicAdd(&deg[dst[e]], 1);
}

__global__ __launch_bounds__(SCAN_B) void k_scan1(const int* __restrict__ deg,
                                                  int* __restrict__ off,
                                                  float* __restrict__ dis,
                                                  int* __restrict__ part) {
    int t = threadIdx.x;
    int i = blockIdx.x * SCAN_B + t;
    int d = (i < V_) ? deg[i] : 0;
    __shared__ int sm[SCAN_B];
    sm[t] = d;
    __syncthreads();
    int val = d;
    for (int s = 1; s < SCAN_B; s <<= 1) {
        int o = (t >= s) ? sm[t - s] : 0;
        __syncthreads();
        val += o;
        sm[t] = val;
        __syncthreads();
    }
    if (i < V_) {
        off[i] = val - d;
        dis[i] = rsqrtf((float)(B_ * d + 1));
    }
    if (t == SCAN_B - 1) part[blockIdx.x] = val;
}

__global__ void k_scan2(int* __restrict__ part) {
    __shared__ int sm[128];
    int t = threadIdx.x;
    int v = (t < SCAN_G) ? part[t] : 0;
    sm[t] = v;
    __syncthreads();
    int val = v;
    for (int s = 1; s < 128; s <<= 1) {
        int o = (t >= s) ? sm[t - s] : 0;
        __syncthreads();
        val += o;
        sm[t] = val;
        __syncthreads();
    }
    if (t < SCAN_G) part[t] = val - v;
}

__global__ __launch_bounds__(SCAN_B) void k_scan3(int* __restrict__ off,
                                                  const int* __restrict__ part) {
    int i = blockIdx.x * SCAN_B + threadIdx.x;
    if (i < V_) off[i] += part[blockIdx.x];
    if (i == 0) off[V_] = E_;
}

__global__ void k_fill(const int* __restrict__ src, const int* __restrict__ dst,
                       const int* __restrict__ off, int* __restrict__ cursor,
                       int* __restrict__ csr) {
    int e = blockIdx.x * 256 + threadIdx.x;
    if (e < E_) {
        int c = dst[e];
        int p = atomicAdd(&cursor[c], 1);
        csr[off[c] + p] = src[e];
    }
}

// ---------------------------------------------------------------------------
// Weight split: bf16 hi/lo planes of conv_W
// ---------------------------------------------------------------------------

__global__ void k_wsplit(const float* __restrict__ W, ushort* __restrict__ Whi,
                         ushort* __restrict__ Wlo) {
    int i = blockIdx.x * 256 + threadIdx.x;   // over L_*H_*H_
    float w = W[i];
    __hip_bfloat16 hb = __float2bfloat16(w);
    float hf = __bfloat162float(hb);
    __hip_bfloat16 lb = __float2bfloat16(w - hf);
    Whi[i] = *(ushort*)&hb;
    Wlo[i] = *(ushort*)&lb;
}

// ---------------------------------------------------------------------------
// Input projection
// ---------------------------------------------------------------------------

__global__ void k_latproj(const float* __restrict__ Win, const float* __restrict__ bin,
                          const float* __restrict__ latent, float* __restrict__ latproj) {
    int t = blockIdx.x * 128 + threadIdx.x;
    if (t >= B_ * H_) return;
    int b = t >> 7, j = t & 127;
    const float* wr = Win + (size_t)j * (LAT_ + 3) + 3;
    const float* lp = latent + (size_t)b * LAT_;
    float s = bin[j];
    for (int k = 0; k < LAT_; k++) s = fmaf(wr[k], lp[k], s);
    latproj[t] = s;
}

// x0 -> split bf16 planes
__global__ void k_x0(const float* __restrict__ xyz, const float* __restrict__ Win,
                     const float* __restrict__ latproj,
                     ushort* __restrict__ xh, ushort* __restrict__ xl) {
    size_t idx = (size_t)blockIdx.x * 256 + threadIdx.x;   // over N_*H_
    int j = (int)(idx & 127);
    size_t node = idx >> 7;
    int v = (int)(node % V_);
    int b = (int)(node / V_);
    const float* wr = Win + (size_t)j * (LAT_ + 3);
    float s = latproj[b * H_ + j];
    s = fmaf(wr[0], xyz[v * 3 + 0], s);
    s = fmaf(wr[1], xyz[v * 3 + 1], s);
    s = fmaf(wr[2], xyz[v * 3 + 2], s);
    s = fmaxf(s, 0.f);
    __hip_bfloat16 hb = __float2bfloat16(s);
    float hf = __bfloat162float(hb);
    __hip_bfloat16 lb = __float2bfloat16(s - hf);
    xh[idx] = *(ushort*)&hb;
    xl[idx] = *(ushort*)&lb;
}

// ---------------------------------------------------------------------------
// Fused layer GEMM (split-bf16 MFMA) + per-node epilogue.
//   rows <  V: write f32 h (aggregation input)
//   rows >= V: x_out = relu(h + bias), split to bf16 hi/lo, written in place
// Block: 512 threads = 8 waves; tile 64 rows x 128 cols; K=128.
// Wave w owns n-slab [16w,16w+16): W frags held in registers (one L2 read).
// x tiles staged in LDS, XOR-swizzled (byte ^= (row&7)<<4) for conflict-free
// ds_read_b64 fragment reads.
// ---------------------------------------------------------------------------

#define LDSB 33792   // max(2*16384 staging, 64*132*4 bounce)

__global__ __launch_bounds__(512) void k_layer(const ushort* __restrict__ xh,
                                               const ushort* __restrict__ xl,
                                               const ushort* __restrict__ Wh,
                                               const ushort* __restrict__ Wl,
                                               const float* __restrict__ bias,
                                               float* __restrict__ h,
                                               ushort* __restrict__ xh_out,
                                               ushort* __restrict__ xl_out) {
    __shared__ __align__(16) char smem[LDSB];
    const int tid = threadIdx.x;
    const int row0 = blockIdx.x * 64;
    const int lane = tid & 63;
    const int wid  = tid >> 6;
    const int l15  = lane & 15;
    const int kg   = lane >> 4;
    const int n0   = wid * 16;

    // ---- W fragments in registers (both planes, all 4 k-steps) ----
    short8 wf[2][4];
    {
        const ushort* Wp[2] = {Wh, Wl};
#pragma unroll
        for (int p = 0; p < 2; p++)
#pragma unroll
            for (int ks = 0; ks < 4; ks++) {
                const ushort* b = Wp[p] + (size_t)(n0 + l15) * 128 + ks * 32 + kg * 4;
                union { short8 v; uint2 u[2]; } u;
                u.u[0] = *(const uint2*)(b);
                u.u[1] = *(const uint2*)(b + 16);
                wf[p][ks] = u.v;
            }
    }

    // ---- stage x tiles (hi, lo) with XOR swizzle ----
    {
        const ushort* xp[2] = {xh, xl};
#pragma unroll
        for (int p = 0; p < 2; p++) {
            char* base = smem + p * 16384;
#pragma unroll
            for (int rep = 0; rep < 2; rep++) {
                int chunk = tid + rep * 512;            // 0..1023 chunks of 16B
                int r  = chunk >> 4;
                int cb = (chunk & 15) * 16;
                uint4 g = *(const uint4*)((const char*)(xp[p] + (size_t)(row0 + r) * 128) + cb);
                *(uint4*)(base + r * 256 + (cb ^ ((r & 7) << 4))) = g;
            }
        }
    }
    __syncthreads();

    // ---- MFMA main loop ----
    f32x4 acc[4];
#pragma unroll
    for (int mt = 0; mt < 4; mt++) acc[mt] = (f32x4){0.f, 0.f, 0.f, 0.f};
#pragma unroll
    for (int mt = 0; mt < 4; mt++) {
        int row = mt * 16 + l15;
        const char* rbh = smem + row * 256;
        const char* rbl = smem + 16384 + row * 256;
        const int swz = (row & 7) << 4;
#pragma unroll
        for (int ks = 0; ks < 4; ks++) {
            int c0 = ks * 64 + kg * 8;
            union { short8 v; uint2 u[2]; } ah, al;
            ah.u[0] = *(const uint2*)(rbh + ((c0) ^ swz));
            ah.u[1] = *(const uint2*)(rbh + ((c0 + 32) ^ swz));
            al.u[0] = *(const uint2*)(rbl + ((c0) ^ swz));
            al.u[1] = *(const uint2*)(rbl + ((c0 + 32) ^ swz));
            acc[mt] = __builtin_amdgcn_mfma_f32_16x16x32_bf16(ah.v, wf[0][ks], acc[mt], 0, 0, 0);
            acc[mt] = __builtin_amdgcn_mfma_f32_16x16x32_bf16(al.v, wf[0][ks], acc[mt], 0, 0, 0);
            acc[mt] = __builtin_amdgcn_mfma_f32_16x16x32_bf16(ah.v, wf[1][ks], acc[mt], 0, 0, 0);
        }
    }
    __syncthreads();

    // ---- bounce accumulators through LDS as f32 [64][132] ----
    float* bb = (float*)smem;
#pragma unroll
    for (int mt = 0; mt < 4; mt++)
#pragma unroll
        for (int j = 0; j < 4; j++)
            bb[(mt * 16 + kg * 4 + j) * 132 + n0 + l15] = acc[mt][j];
    __syncthreads();

    // ---- epilogue: 512 threads, each 1 row-slice of 16 cols ----
    {
        int r  = tid >> 3;
        int c0 = (tid & 7) * 16;
        int grow = row0 + r;
        float v[16];
#pragma unroll
        for (int i = 0; i < 16; i += 4) {
            f32x4 q = *(const f32x4*)(&bb[r * 132 + c0 + i]);
            v[i + 0] = q[0]; v[i + 1] = q[1]; v[i + 2] = q[2]; v[i + 3] = q[3];
        }
        if (grow < V_) {
            float* hp = h + (size_t)grow * 128 + c0;
#pragma unroll
            for (int i = 0; i < 16; i += 4) {
                f32x4 q = {v[i], v[i + 1], v[i + 2], v[i + 3]};
                *(f32x4*)(hp + i) = q;
            }
        } else {
            ushort hs[16], ls[16];
#pragma unroll
            for (int i = 0; i < 16; i++) {
                float vv = fmaxf(v[i] + bias[c0 + i], 0.f);
                __hip_bfloat16 hb = __float2bfloat16(vv);
                float hf = __bfloat162float(hb);
                __hip_bfloat16 lb = __float2bfloat16(vv - hf);
                hs[i] = *(ushort*)&hb;
                ls[i] = *(ushort*)&lb;
            }
            char* ph = (char*)(xh_out + (size_t)grow * 128 + c0);
            char* pl = (char*)(xl_out + (size_t)grow * 128 + c0);
            *(uint4*)(ph)      = *(uint4*)&hs[0];
            *(uint4*)(ph + 16) = *(uint4*)&hs[8];
            *(uint4*)(pl)      = *(uint4*)&ls[0];
            *(uint4*)(pl + 16) = *(uint4*)&ls[8];
        }
    }
}

// ---------------------------------------------------------------------------
// Aggregation for batch-0 nodes only (c < V). One wave per node.
// x[c] = relu(dis_c*B*sum dis_u*h[u] + dis_c^2*h[c] + bias) -> bf16 hi/lo
// ---------------------------------------------------------------------------

__global__ __launch_bounds__(256) void k_agg0(const float* __restrict__ h,
                                              const float* __restrict__ dis,
                                              const int* __restrict__ off,
                                              const int* __restrict__ csr,
                                              const float* __restrict__ bias,
                                              ushort* __restrict__ xh_out,
                                              ushort* __restrict__ xl_out) {
    int c = blockIdx.x * 4 + (threadIdx.x >> 6);
    int lane = threadIdx.x & 63;
    if (c >= V_) return;
    float dc = dis[c];
    float a0 = 0.f, a1 = 0.f;
    int beg = off[c], end = off[c + 1];
    for (int i = beg; i < end; i++) {
        int u = csr[i];
        float wu = dis[u];
        const float* hu = h + (size_t)u * 128;
        a0 = fmaf(wu, hu[lane],      a0);
        a1 = fmaf(wu, hu[lane + 64], a1);
    }
    const float* hr = h + (size_t)c * 128;
    float s0 = fmaxf(dc * (float)B_ * a0 + dc * dc * hr[lane]      + bias[lane],      0.f);
    float s1 = fmaxf(dc * (float)B_ * a1 + dc * dc * hr[lane + 64] + bias[lane + 64], 0.f);
    __hip_bfloat16 h0 = __float2bfloat16(s0);
    __hip_bfloat16 l0 = __float2bfloat16(s0 - __bfloat162float(h0));
    __hip_bfloat16 h1 = __float2bfloat16(s1);
    __hip_bfloat16 l1 = __float2bfloat16(s1 - __bfloat162float(h1));
    xh_out[(size_t)c * 128 + lane]      = *(ushort*)&h0;
    xl_out[(size_t)c * 128 + lane]      = *(ushort*)&l0;
    xh_out[(size_t)c * 128 + lane + 64] = *(ushort*)&h1;
    xl_out[(size_t)c * 128 + lane + 64] = *(ushort*)&l1;
}

// ---------------------------------------------------------------------------
// Output head from bf16 hi/lo planes. One wave per node.
// ---------------------------------------------------------------------------

__global__ __launch_bounds__(256) void k_out(const ushort* __restrict__ xh,
                                             const ushort* __restrict__ xl,
                                             const float* __restrict__ Wout,
                                             const float* __restrict__ bout,
                                             float* __restrict__ out) {
    int n = (int)(((size_t)blockIdx.x * 256 + threadIdx.x) >> 6);
    int lane = threadIdx.x & 63;
    if (n >= N_) return;
    const ushort* ph = xh + (size_t)n * 128;
    const ushort* pl = xl + (size_t)n * 128;
    ushort u0h = ph[lane], u0l = pl[lane], u1h = ph[lane + 64], u1l = pl[lane + 64];
    float x0 = __bfloat162float(*(__hip_bfloat16*)&u0h) + __bfloat162float(*(__hip_bfloat16*)&u0l);
    float x1 = __bfloat162float(*(__hip_bfloat16*)&u1h) + __bfloat162float(*(__hip_bfloat16*)&u1l);
#pragma unroll
    for (int o = 0; o < 3; o++) {
        float a = x0 * Wout[o * 128 + lane] + x1 * Wout[o * 128 + 64 + lane];
#pragma unroll
        for (int d = 32; d; d >>= 1) a += __shfl_down(a, d);
        if (lane == 0) out[(size_t)n * 3 + o] = a + bout[o];
    }
}

// ---------------------------------------------------------------------------

extern "C" void kernel_launch(void* const* d_in, const int* in_sizes, int n_in,
                              void* d_out, int out_size, void* d_ws, size_t ws_size,
                              hipStream_t stream) {
    const float* xyz    = (const float*)d_in[0];
    const float* latent = (const float*)d_in[1];
    const int*   ei     = (const int*)d_in[2];
    const float* Win    = (const float*)d_in[3];
    const float* bin    = (const float*)d_in[4];
    const float* convW  = (const float*)d_in[5];
    const float* convb  = (const float*)d_in[6];
    const float* Wout   = (const float*)d_in[7];
    const float* bout   = (const float*)d_in[8];
    float* out = (float*)d_out;

    char* w = (char*)d_ws;
    auto carve = [&](size_t bytes) {
        char* p = w;
        w += (bytes + 255) & ~(size_t)255;
        return p;
    };
    ushort* xh      = (ushort*)carve((size_t)N_ * H_ * 2);
    ushort* xl      = (ushort*)carve((size_t)N_ * H_ * 2);
    float*  h       = (float*)carve((size_t)V_ * H_ * 4);
    ushort* Whi     = (ushort*)carve((size_t)L_ * H_ * H_ * 2);
    ushort* Wlo     = (ushort*)carve((size_t)L_ * H_ * H_ * 2);
    float*  dis     = (float*)carve((size_t)V_ * 4);
    float*  latproj = (float*)carve((size_t)B_ * H_ * 4);
    int*    deg     = (int*)carve((size_t)V_ * 4);
    int*    off     = (int*)carve((size_t)(V_ + 1) * 4);
    int*    cursor  = (int*)carve((size_t)V_ * 4);
    int*    csr     = (int*)carve((size_t)E_ * 4);
    int*    part    = (int*)carve((size_t)SCAN_G * 4);
    (void)ws_size; (void)in_sizes; (void)n_in; (void)out_size;

    const int* src = ei;
    const int* dst = ei + E_;

    k_zero<<<(V_ + 255) / 256, 256, 0, stream>>>(deg, cursor);
    k_deg<<<(E_ + 255) / 256, 256, 0, stream>>>(dst, deg);
    k_scan1<<<SCAN_G, SCAN_B, 0, stream>>>(deg, off, dis, part);
    k_scan2<<<1, 128, 0, stream>>>(part);
    k_scan3<<<SCAN_G, SCAN_B, 0, stream>>>(off, part);
    k_fill<<<(E_ + 255) / 256, 256, 0, stream>>>(src, dst, off, cursor, csr);

    k_wsplit<<<(L_ * H_ * H_) / 256, 256, 0, stream>>>(convW, Whi, Wlo);
    k_latproj<<<4, 128, 0, stream>>>(Win, bin, latent, latproj);
    k_x0<<<(int)(((size_t)N_ * H_) / 256), 256, 0, stream>>>(xyz, Win, latproj, xh, xl);

    for (int l = 0; l < L_; l++) {
        k_layer<<<N_ / 64, 512, 0, stream>>>(xh, xl,
                                             Whi + (size_t)l * H_ * H_,
                                             Wlo + (size_t)l * H_ * H_,
                                             convb + (size_t)l * H_,
                                             h, xh, xl);
        k_agg0<<<(V_ + 3) / 4, 256, 0, stream>>>(h, dis, off, csr,
                                                 convb + (size_t)l * H_, xh, xl);
    }

    k_out<<<N_ / 4, 256, 0, stream>>>(xh, xl, Wout, bout, out);
}

// Round 4
// 436.260 us; speedup vs baseline: 1.5672x; 1.1562x over previous
//
#include <hip/hip_runtime.h>
#include <hip/hip_bf16.h>

typedef __attribute__((ext_vector_type(8))) short short8;
typedef __attribute__((ext_vector_type(4))) float f32x4;

#define V_ 50000
#define E_ 300000
#define B_ 4
#define LAT_ 512
#define H_ 128
#define L_ 3
#define N_ (B_*V_)

#define SCAN_B 512
#define SCAN_G ((V_ + SCAN_B - 1) / SCAN_B)   // 98

__device__ inline void bsplit(float v, ushort& hi, ushort& lo) {
    __hip_bfloat16 hb = __float2bfloat16(v);
    float hf = __bfloat162float(hb);
    __hip_bfloat16 lb = __float2bfloat16(v - hf);
    hi = *(ushort*)&hb; lo = *(ushort*)&lb;
}
__device__ inline float bjoin(ushort h, ushort l) {
    __hip_bfloat16 hb = *(__hip_bfloat16*)&h;
    __hip_bfloat16 lb = *(__hip_bfloat16*)&l;
    return __bfloat162float(hb) + __bfloat162float(lb);
}

// ---------------------------------------------------------------------------
// Graph preprocessing
// ---------------------------------------------------------------------------

__global__ void k_zero(int* __restrict__ deg, int* __restrict__ cursor) {
    int i = blockIdx.x * 256 + threadIdx.x;
    if (i < V_) { deg[i] = 0; cursor[i] = 0; }
}

__global__ void k_deg(const int* __restrict__ dst, int* __restrict__ deg) {
    int e = blockIdx.x * 256 + threadIdx.x;
    if (e < E_) atomicAdd(&deg[dst[e]], 1);
}

__global__ __launch_bounds__(SCAN_B) void k_scan1(const int* __restrict__ deg,
                                                  int* __restrict__ off,
                                                  float* __restrict__ dis,
                                                  int* __restrict__ part) {
    int t = threadIdx.x;
    int i = blockIdx.x * SCAN_B + t;
    int d = (i < V_) ? deg[i] : 0;
    __shared__ int sm[SCAN_B];
    sm[t] = d;
    __syncthreads();
    int val = d;
    for (int s = 1; s < SCAN_B; s <<= 1) {
        int o = (t >= s) ? sm[t - s] : 0;
        __syncthreads();
        val += o;
        sm[t] = val;
        __syncthreads();
    }
    if (i < V_) {
        off[i] = val - d;
        dis[i] = rsqrtf((float)(B_ * d + 1));
    }
    if (t == SCAN_B - 1) part[blockIdx.x] = val;
}

__global__ void k_scan2(int* __restrict__ part) {
    __shared__ int sm[128];
    int t = threadIdx.x;
    int v = (t < SCAN_G) ? part[t] : 0;
    sm[t] = v;
    __syncthreads();
    int val = v;
    for (int s = 1; s < 128; s <<= 1) {
        int o = (t >= s) ? sm[t - s] : 0;
        __syncthreads();
        val += o;
        sm[t] = val;
        __syncthreads();
    }
    if (t < SCAN_G) part[t] = val - v;
}

__global__ __launch_bounds__(SCAN_B) void k_scan3(int* __restrict__ off,
                                                  const int* __restrict__ part) {
    int i = blockIdx.x * SCAN_B + threadIdx.x;
    if (i < V_) off[i] += part[blockIdx.x];
    if (i == 0) off[V_] = E_;
}

__global__ void k_fill(const int* __restrict__ src, const int* __restrict__ dst,
                       const int* __restrict__ off, int* __restrict__ cursor,
                       int* __restrict__ csr) {
    int e = blockIdx.x * 256 + threadIdx.x;
    if (e < E_) {
        int c = dst[e];
        int p = atomicAdd(&cursor[c], 1);
        csr[off[c] + p] = src[e];
    }
}

// ---------------------------------------------------------------------------
// Weight split + latent projection
// ---------------------------------------------------------------------------

__global__ void k_wsplit(const float* __restrict__ W, ushort* __restrict__ Whi,
                         ushort* __restrict__ Wlo) {
    int i = blockIdx.x * 256 + threadIdx.x;
    float w = W[i];
    ushort hi, lo; bsplit(w, hi, lo);
    Whi[i] = hi; Wlo[i] = lo;
}

__global__ void k_latproj(const float* __restrict__ Win, const float* __restrict__ bin,
                          const float* __restrict__ latent, float* __restrict__ latproj) {
    int t = blockIdx.x * 128 + threadIdx.x;
    if (t >= B_ * H_) return;
    int b = t >> 7, j = t & 127;
    const float* wr = Win + (size_t)j * (LAT_ + 3) + 3;
    const float* lp = latent + (size_t)b * LAT_;
    float s = bin[j];
    for (int k = 0; k < LAT_; k++) s = fmaf(wr[k], lp[k], s);
    latproj[t] = s;
}

// ---------------------------------------------------------------------------
// k_big: rows >= V (batches 1..3) have NO edges -> fully fused
// x0 -> 3 x (split-bf16 MFMA layer) -> output head, all in LDS.
// 512 thr = 8 waves; tile 64 rows x 128 cols; wave = 16-col slab.
// LDS: 2 ping-pong buffers, each [2 planes][64 rows][256B], XOR-swizzled rows.
// ---------------------------------------------------------------------------

__global__ __launch_bounds__(512, 4) void k_big(
        const float* __restrict__ xyz, const float* __restrict__ latproj,
        const float* __restrict__ Win,
        const ushort* __restrict__ Whi, const ushort* __restrict__ Wlo,
        const float* __restrict__ convb,
        const float* __restrict__ Wout, const float* __restrict__ bout,
        float* __restrict__ out) {
    __shared__ __align__(16) char smem[65536];
    const int tid = threadIdx.x;
    const int row0 = V_ + blockIdx.x * 64;
    const int lane = tid & 63;
    const int wid  = tid >> 6;
    const int l15  = lane & 15;
    const int kg   = lane >> 4;
    const int n0   = wid * 16;
    const int tr   = tid >> 4;          // 0..31
    const int c0   = (tid & 15) * 8;

    // ---- x0 into buffer 0 ----
#pragma unroll
    for (int rep = 0; rep < 2; rep++) {
        int row = tr + rep * 32;
        int node = row0 + row;
        ushort hs[8], ls[8];
        if (node < N_) {
            int v = node % V_, b = node / V_;
            float xv0 = xyz[v*3+0], xv1 = xyz[v*3+1], xv2 = xyz[v*3+2];
#pragma unroll
            for (int i = 0; i < 8; i++) {
                int j = c0 + i;
                float s = latproj[b*H_ + j];
                s = fmaf(Win[(size_t)j*(LAT_+3)+0], xv0, s);
                s = fmaf(Win[(size_t)j*(LAT_+3)+1], xv1, s);
                s = fmaf(Win[(size_t)j*(LAT_+3)+2], xv2, s);
                s = fmaxf(s, 0.f);
                bsplit(s, hs[i], ls[i]);
            }
        } else {
#pragma unroll
            for (int i = 0; i < 8; i++) { hs[i] = 0; ls[i] = 0; }
        }
        int bo = (c0*2) ^ ((row & 7) << 4);
        *(uint4*)(smem + row*256 + bo) = *(uint4*)hs;
        *(uint4*)(smem + 16384 + row*256 + bo) = *(uint4*)ls;
    }
    __syncthreads();

    int cur = 0;
    for (int l = 0; l < L_; l++) {
        const ushort* Whp = Whi + (size_t)l*H_*H_;
        const ushort* Wlp = Wlo + (size_t)l*H_*H_;
        short8 wh[4], wl[4];
#pragma unroll
        for (int ks = 0; ks < 4; ks++) {
            const ushort* bh = Whp + (size_t)(n0 + l15)*H_ + ks*32 + kg*4;
            const ushort* bl = Wlp + (size_t)(n0 + l15)*H_ + ks*32 + kg*4;
            union { short8 v; uint2 u[2]; } uh, ul;
            uh.u[0] = *(const uint2*)bh;  uh.u[1] = *(const uint2*)(bh + 16);
            ul.u[0] = *(const uint2*)bl;  ul.u[1] = *(const uint2*)(bl + 16);
            wh[ks] = uh.v; wl[ks] = ul.v;
        }
        const char* sb = smem + cur*32768;
        f32x4 acc[4];
#pragma unroll
        for (int mt = 0; mt < 4; mt++) acc[mt] = (f32x4){0.f,0.f,0.f,0.f};
#pragma unroll
        for (int mt = 0; mt < 4; mt++) {
            int row = mt*16 + l15;
            int swz = (row & 7) << 4;
            const char* rbh = sb + row*256;
            const char* rbl = sb + 16384 + row*256;
#pragma unroll
            for (int ks = 0; ks < 4; ks++) {
                int cc = ks*64 + kg*8;
                union { short8 v; uint2 u[2]; } ah, al;
                ah.u[0] = *(const uint2*)(rbh + (cc ^ swz));
                ah.u[1] = *(const uint2*)(rbh + ((cc+32) ^ swz));
                al.u[0] = *(const uint2*)(rbl + (cc ^ swz));
                al.u[1] = *(const uint2*)(rbl + ((cc+32) ^ swz));
                acc[mt] = __builtin_amdgcn_mfma_f32_16x16x32_bf16(ah.v, wh[ks], acc[mt], 0,0,0);
                acc[mt] = __builtin_amdgcn_mfma_f32_16x16x32_bf16(al.v, wh[ks], acc[mt], 0,0,0);
                acc[mt] = __builtin_amdgcn_mfma_f32_16x16x32_bf16(ah.v, wl[ks], acc[mt], 0,0,0);
            }
        }
        __syncthreads();
        char* db = smem + (cur^1)*32768;
        float bv = convb[l*H_ + n0 + l15];
        int bo = (n0 + l15) * 2;
#pragma unroll
        for (int mt = 0; mt < 4; mt++)
#pragma unroll
            for (int j = 0; j < 4; j++) {
                int row = mt*16 + kg*4 + j;
                int swz = (row & 7) << 4;
                float v = fmaxf(acc[mt][j] + bv, 0.f);
                ushort hi, lo; bsplit(v, hi, lo);
                *(ushort*)(db + row*256 + (bo ^ swz)) = hi;
                *(ushort*)(db + 16384 + row*256 + (bo ^ swz)) = lo;
            }
        __syncthreads();
        cur ^= 1;
    }

    // ---- output head: out = x3 . Wout^T + bout ----
    const char* ob = smem + cur*32768;
    float wo0[8], wo1[8], wo2[8];
#pragma unroll
    for (int i = 0; i < 8; i++) {
        wo0[i] = Wout[0*H_ + c0 + i];
        wo1[i] = Wout[1*H_ + c0 + i];
        wo2[i] = Wout[2*H_ + c0 + i];
    }
#pragma unroll
    for (int rep = 0; rep < 2; rep++) {
        int row = tr + rep*32;
        int node = row0 + row;
        int bo = (c0*2) ^ ((row & 7) << 4);
        uint4 uh = *(const uint4*)(ob + row*256 + bo);
        uint4 ul = *(const uint4*)(ob + 16384 + row*256 + bo);
        const ushort* hp = (const ushort*)&uh;
        const ushort* lp = (const ushort*)&ul;
        float p0 = 0.f, p1 = 0.f, p2 = 0.f;
#pragma unroll
        for (int i = 0; i < 8; i++) {
            float xv = bjoin(hp[i], lp[i]);
            p0 = fmaf(xv, wo0[i], p0);
            p1 = fmaf(xv, wo1[i], p1);
            p2 = fmaf(xv, wo2[i], p2);
        }
#pragma unroll
        for (int m = 1; m < 16; m <<= 1) {
            p0 += __shfl_xor(p0, m);
            p1 += __shfl_xor(p1, m);
            p2 += __shfl_xor(p2, m);
        }
        if ((tid & 15) == 0 && node < N_) {
            out[(size_t)node*3 + 0] = p0 + bout[0];
            out[(size_t)node*3 + 1] = p1 + bout[1];
            out[(size_t)node*3 + 2] = p2 + bout[2];
        }
    }
}

// ---------------------------------------------------------------------------
// k_layerb0: batch-0 GEMM h = x @ W^T for rows < V.  256 thr = 4 waves,
// tile 32 rows x 128 cols; wave = 32-col slab (2 n-tiles).
// MODE 0: compute x0 into LDS (layer 1).  MODE 1: stage xh/xl from global.
// Epilogue: write f32 h (aggregation input).
// ---------------------------------------------------------------------------

template<int MODE>
__global__ __launch_bounds__(256, 4) void k_layerb0(
        const ushort* __restrict__ xh, const ushort* __restrict__ xl,
        const float* __restrict__ xyz, const float* __restrict__ latproj,
        const float* __restrict__ Win,
        const ushort* __restrict__ Whp, const ushort* __restrict__ Wlp,
        float* __restrict__ h) {
    __shared__ __align__(16) char smem[16896];   // stage 16384 | bounce 32*132*4
    const int tid = threadIdx.x;
    const int row0 = blockIdx.x * 32;
    const int lane = tid & 63;
    const int wid  = tid >> 6;
    const int l15  = lane & 15;
    const int kg   = lane >> 4;
    const int n0   = wid * 32;
    const int tr   = tid >> 4;          // 0..15
    const int c0   = (tid & 15) * 8;

    if (MODE == 0) {
#pragma unroll
        for (int rep = 0; rep < 2; rep++) {
            int row = tr + rep * 16;
            int v = row0 + row;
            ushort hs[8], ls[8];
            if (v < V_) {
                float xv0 = xyz[v*3+0], xv1 = xyz[v*3+1], xv2 = xyz[v*3+2];
#pragma unroll
                for (int i = 0; i < 8; i++) {
                    int j = c0 + i;
                    float s = latproj[j];                       // b = 0
                    s = fmaf(Win[(size_t)j*(LAT_+3)+0], xv0, s);
                    s = fmaf(Win[(size_t)j*(LAT_+3)+1], xv1, s);
                    s = fmaf(Win[(size_t)j*(LAT_+3)+2], xv2, s);
                    s = fmaxf(s, 0.f);
                    bsplit(s, hs[i], ls[i]);
                }
            } else {
#pragma unroll
                for (int i = 0; i < 8; i++) { hs[i] = 0; ls[i] = 0; }
            }
            int bo = (c0*2) ^ ((row & 7) << 4);
            *(uint4*)(smem + row*256 + bo) = *(uint4*)hs;
            *(uint4*)(smem + 8192 + row*256 + bo) = *(uint4*)ls;
        }
    } else {
#pragma unroll
        for (int k = 0; k < 4; k++) {
            int chunk = tid + k*256;
            int p  = chunk >> 9;
            int r  = (chunk >> 4) & 31;
            int cb = (chunk & 15) * 16;
            int grow = row0 + r;
            uint4 g = {0u,0u,0u,0u};
            if (grow < V_)
                g = *(const uint4*)((const char*)((p ? xl : xh) + (size_t)grow*H_) + cb);
            *(uint4*)(smem + p*8192 + r*256 + (cb ^ ((r & 7) << 4))) = g;
        }
    }
    __syncthreads();

    short8 wh[2][4], wl[2][4];
#pragma unroll
    for (int nt = 0; nt < 2; nt++)
#pragma unroll
        for (int ks = 0; ks < 4; ks++) {
            const ushort* bh = Whp + (size_t)(n0 + nt*16 + l15)*H_ + ks*32 + kg*4;
            const ushort* bl = Wlp + (size_t)(n0 + nt*16 + l15)*H_ + ks*32 + kg*4;
            union { short8 v; uint2 u[2]; } uh, ul;
            uh.u[0] = *(const uint2*)bh;  uh.u[1] = *(const uint2*)(bh + 16);
            ul.u[0] = *(const uint2*)bl;  ul.u[1] = *(const uint2*)(bl + 16);
            wh[nt][ks] = uh.v; wl[nt][ks] = ul.v;
        }

    f32x4 acc[2][2];
#pragma unroll
    for (int mt = 0; mt < 2; mt++)
#pragma unroll
        for (int nt = 0; nt < 2; nt++) acc[mt][nt] = (f32x4){0.f,0.f,0.f,0.f};
#pragma unroll
    for (int mt = 0; mt < 2; mt++) {
        int row = mt*16 + l15;
        int swz = (row & 7) << 4;
        const char* rbh = smem + row*256;
        const char* rbl = smem + 8192 + row*256;
#pragma unroll
        for (int ks = 0; ks < 4; ks++) {
            int cc = ks*64 + kg*8;
            union { short8 v; uint2 u[2]; } ah, al;
            ah.u[0] = *(const uint2*)(rbh + (cc ^ swz));
            ah.u[1] = *(const uint2*)(rbh + ((cc+32) ^ swz));
            al.u[0] = *(const uint2*)(rbl + (cc ^ swz));
            al.u[1] = *(const uint2*)(rbl + ((cc+32) ^ swz));
#pragma unroll
            for (int nt = 0; nt < 2; nt++) {
                acc[mt][nt] = __builtin_amdgcn_mfma_f32_16x16x32_bf16(ah.v, wh[nt][ks], acc[mt][nt], 0,0,0);
                acc[mt][nt] = __builtin_amdgcn_mfma_f32_16x16x32_bf16(al.v, wh[nt][ks], acc[mt][nt], 0,0,0);
                acc[mt][nt] = __builtin_amdgcn_mfma_f32_16x16x32_bf16(ah.v, wl[nt][ks], acc[mt][nt], 0,0,0);
            }
        }
    }
    __syncthreads();

    float* bb = (float*)smem;
#pragma unroll
    for (int mt = 0; mt < 2; mt++)
#pragma unroll
        for (int nt = 0; nt < 2; nt++)
#pragma unroll
            for (int j = 0; j < 4; j++)
                bb[(mt*16 + kg*4 + j)*132 + n0 + nt*16 + l15] = acc[mt][nt][j];
    __syncthreads();

#pragma unroll
    for (int rep = 0; rep < 2; rep++) {
        int row = tr + rep*16;
        int grow = row0 + row;
        if (grow < V_) {
            f32x4 a = *(const f32x4*)&bb[row*132 + c0];
            f32x4 b = *(const f32x4*)&bb[row*132 + c0 + 4];
            *(f32x4*)(h + (size_t)grow*H_ + c0)     = a;
            *(f32x4*)(h + (size_t)grow*H_ + c0 + 4) = b;
        }
    }
}

// ---------------------------------------------------------------------------
// Aggregation (batch-0 nodes).  One wave per node; lane-parallel CSR prefetch.
// FINAL: fuse output head instead of writing x'.
// ---------------------------------------------------------------------------

template<bool FINAL>
__global__ __launch_bounds__(256) void k_agg0(const float* __restrict__ h,
                                              const float* __restrict__ dis,
                                              const int* __restrict__ off,
                                              const int* __restrict__ csr,
                                              const float* __restrict__ bias,
                                              ushort* __restrict__ xh_out,
                                              ushort* __restrict__ xl_out,
                                              const float* __restrict__ Wout,
                                              const float* __restrict__ bout,
                                              float* __restrict__ out) {
    int c = blockIdx.x * 4 + (threadIdx.x >> 6);
    int lane = threadIdx.x & 63;
    if (c >= V_) return;
    int beg = off[c], end = off[c + 1];
    int nu = end - beg;
    int   myu  = (lane < nu) ? csr[beg + lane] : 0;
    float mywu = (lane < nu) ? dis[myu] : 0.f;
    float a0 = 0.f, a1 = 0.f;
    int nn = nu < 64 ? nu : 64;
    for (int i = 0; i < nn; i++) {
        int u = __shfl(myu, i);
        float wu = __shfl(mywu, i);
        const float* hu = h + (size_t)u * 128;
        a0 = fmaf(wu, hu[lane],      a0);
        a1 = fmaf(wu, hu[lane + 64], a1);
    }
    for (int i = beg + 64; i < end; i++) {       // rare high-degree tail
        int u = csr[i];
        float wu = dis[u];
        const float* hu = h + (size_t)u * 128;
        a0 = fmaf(wu, hu[lane],      a0);
        a1 = fmaf(wu, hu[lane + 64], a1);
    }
    float dc = dis[c];
    const float* hr = h + (size_t)c * 128;
    float s0 = fmaxf(dc * (float)B_ * a0 + dc * dc * hr[lane]      + bias[lane],      0.f);
    float s1 = fmaxf(dc * (float)B_ * a1 + dc * dc * hr[lane + 64] + bias[lane + 64], 0.f);
    if (FINAL) {
        float p0 = s0 * Wout[0*H_ + lane] + s1 * Wout[0*H_ + 64 + lane];
        float p1 = s0 * Wout[1*H_ + lane] + s1 * Wout[1*H_ + 64 + lane];
        float p2 = s0 * Wout[2*H_ + lane] + s1 * Wout[2*H_ + 64 + lane];
#pragma unroll
        for (int d = 32; d; d >>= 1) {
            p0 += __shfl_down(p0, d);
            p1 += __shfl_down(p1, d);
            p2 += __shfl_down(p2, d);
        }
        if (lane == 0) {
            out[(size_t)c*3 + 0] = p0 + bout[0];
            out[(size_t)c*3 + 1] = p1 + bout[1];
            out[(size_t)c*3 + 2] = p2 + bout[2];
        }
    } else {
        ushort h0, l0, h1, l1;
        bsplit(s0, h0, l0);
        bsplit(s1, h1, l1);
        xh_out[(size_t)c*128 + lane]      = h0;
        xl_out[(size_t)c*128 + lane]      = l0;
        xh_out[(size_t)c*128 + lane + 64] = h1;
        xl_out[(size_t)c*128 + lane + 64] = l1;
    }
}

// ---------------------------------------------------------------------------

extern "C" void kernel_launch(void* const* d_in, const int* in_sizes, int n_in,
                              void* d_out, int out_size, void* d_ws, size_t ws_size,
                              hipStream_t stream) {
    const float* xyz    = (const float*)d_in[0];
    const float* latent = (const float*)d_in[1];
    const int*   ei     = (const int*)d_in[2];
    const float* Win    = (const float*)d_in[3];
    const float* bin    = (const float*)d_in[4];
    const float* convW  = (const float*)d_in[5];
    const float* convb  = (const float*)d_in[6];
    const float* Wout   = (const float*)d_in[7];
    const float* bout   = (const float*)d_in[8];
    float* out = (float*)d_out;

    char* w = (char*)d_ws;
    auto carve = [&](size_t bytes) {
        char* p = w;
        w += (bytes + 255) & ~(size_t)255;
        return p;
    };
    ushort* xh      = (ushort*)carve((size_t)V_ * H_ * 2);
    ushort* xl      = (ushort*)carve((size_t)V_ * H_ * 2);
    float*  h       = (float*)carve((size_t)V_ * H_ * 4);
    ushort* Whi     = (ushort*)carve((size_t)L_ * H_ * H_ * 2);
    ushort* Wlo     = (ushort*)carve((size_t)L_ * H_ * H_ * 2);
    float*  dis     = (float*)carve((size_t)V_ * 4);
    float*  latproj = (float*)carve((size_t)B_ * H_ * 4);
    int*    deg     = (int*)carve((size_t)V_ * 4);
    int*    off     = (int*)carve((size_t)(V_ + 1) * 4);
    int*    cursor  = (int*)carve((size_t)V_ * 4);
    int*    csr     = (int*)carve((size_t)E_ * 4);
    int*    part    = (int*)carve((size_t)SCAN_G * 4);
    (void)ws_size; (void)in_sizes; (void)n_in; (void)out_size;

    const int* src = ei;
    const int* dst = ei + E_;

    k_zero<<<(V_ + 255) / 256, 256, 0, stream>>>(deg, cursor);
    k_deg<<<(E_ + 255) / 256, 256, 0, stream>>>(dst, deg);
    k_scan1<<<SCAN_G, SCAN_B, 0, stream>>>(deg, off, dis, part);
    k_scan2<<<1, 128, 0, stream>>>(part);
    k_scan3<<<SCAN_G, SCAN_B, 0, stream>>>(off, part);
    k_fill<<<(E_ + 255) / 256, 256, 0, stream>>>(src, dst, off, cursor, csr);

    k_wsplit<<<(L_ * H_ * H_) / 256, 256, 0, stream>>>(convW, Whi, Wlo);
    k_latproj<<<4, 128, 0, stream>>>(Win, bin, latent, latproj);

    // batches 1..3: fully fused (no graph)
    k_big<<<(N_ - V_ + 63) / 64, 512, 0, stream>>>(xyz, latproj, Win, Whi, Wlo,
                                                   convb, Wout, bout, out);

    // batch 0 chain
    const int GB0 = (V_ + 31) / 32;
    k_layerb0<0><<<GB0, 256, 0, stream>>>(nullptr, nullptr, xyz, latproj, Win,
                                          Whi, Wlo, h);
    k_agg0<false><<<(V_ + 3) / 4, 256, 0, stream>>>(h, dis, off, csr, convb,
                                                    xh, xl, nullptr, nullptr, nullptr);
    k_layerb0<1><<<GB0, 256, 0, stream>>>(xh, xl, nullptr, nullptr, nullptr,
                                          Whi + (size_t)1*H_*H_, Wlo + (size_t)1*H_*H_, h);
    k_agg0<false><<<(V_ + 3) / 4, 256, 0, stream>>>(h, dis, off, csr, convb + 1*H_,
                                                    xh, xl, nullptr, nullptr, nullptr);
    k_layerb0<1><<<GB0, 256, 0, stream>>>(xh, xl, nullptr, nullptr, nullptr,
                                          Whi + (size_t)2*H_*H_, Wlo + (size_t)2*H_*H_, h);
    k_agg0<true><<<(V_ + 3) / 4, 256, 0, stream>>>(h, dis, off, csr, convb + 2*H_,
                                                   nullptr, nullptr, Wout, bout, out);
}

// Round 5
// 416.083 us; speedup vs baseline: 1.6432x; 1.0485x over previous
//
#include <hip/hip_runtime.h>
#include <hip/hip_bf16.h>

typedef __attribute__((ext_vector_type(8))) short short8;
typedef __attribute__((ext_vector_type(4))) float f32x4;

#define V_ 50000
#define E_ 300000
#define B_ 4
#define LAT_ 512
#define H_ 128
#define L_ 3
#define N_ (B_*V_)

#define SCAN_B 512
#define SCAN_G ((V_ + SCAN_B - 1) / SCAN_B)   // 98

__device__ inline void bsplit(float v, ushort& hi, ushort& lo) {
    __hip_bfloat16 hb = __float2bfloat16(v);
    float hf = __bfloat162float(hb);
    __hip_bfloat16 lb = __float2bfloat16(v - hf);
    hi = *(ushort*)&hb; lo = *(ushort*)&lb;
}
__device__ inline float bjoin(ushort h, ushort l) {
    __hip_bfloat16 hb = *(__hip_bfloat16*)&h;
    __hip_bfloat16 lb = *(__hip_bfloat16*)&l;
    return __bfloat162float(hb) + __bfloat162float(lb);
}
// row swizzle: write-phase kg-rows {j,j+4,j+8,j+12} map to 4 disjoint bank sets;
// read-phase (16 consecutive rows) stays 2-way (free).
__device__ inline int swzr(int row) { return ((row & 7) << 4) ^ ((row & 8) << 2); }

// ---------------------------------------------------------------------------
// Graph preprocessing
// ---------------------------------------------------------------------------

__global__ void k_zero(int* __restrict__ deg, int* __restrict__ cursor) {
    int i = blockIdx.x * 256 + threadIdx.x;
    if (i < V_) { deg[i] = 0; cursor[i] = 0; }
}

__global__ void k_deg(const int* __restrict__ dst, int* __restrict__ deg) {
    int e = blockIdx.x * 256 + threadIdx.x;
    if (e < E_) atomicAdd(&deg[dst[e]], 1);
}

__global__ __launch_bounds__(SCAN_B) void k_scan1(const int* __restrict__ deg,
                                                  int* __restrict__ off,
                                                  float* __restrict__ dis,
                                                  int* __restrict__ part) {
    int t = threadIdx.x;
    int i = blockIdx.x * SCAN_B + t;
    int d = (i < V_) ? deg[i] : 0;
    __shared__ int sm[SCAN_B];
    sm[t] = d;
    __syncthreads();
    int val = d;
    for (int s = 1; s < SCAN_B; s <<= 1) {
        int o = (t >= s) ? sm[t - s] : 0;
        __syncthreads();
        val += o;
        sm[t] = val;
        __syncthreads();
    }
    if (i < V_) {
        off[i] = val - d;
        dis[i] = rsqrtf((float)(B_ * d + 1));
    }
    if (t == SCAN_B - 1) part[blockIdx.x] = val;
}

__global__ void k_scan2(int* __restrict__ part) {
    __shared__ int sm[128];
    int t = threadIdx.x;
    int v = (t < SCAN_G) ? part[t] : 0;
    sm[t] = v;
    __syncthreads();
    int val = v;
    for (int s = 1; s < 128; s <<= 1) {
        int o = (t >= s) ? sm[t - s] : 0;
        __syncthreads();
        val += o;
        sm[t] = val;
        __syncthreads();
    }
    if (t < SCAN_G) part[t] = val - v;
}

__global__ __launch_bounds__(SCAN_B) void k_scan3(int* __restrict__ off,
                                                  const int* __restrict__ part) {
    int i = blockIdx.x * SCAN_B + threadIdx.x;
    if (i < V_) off[i] += part[blockIdx.x];
    if (i == 0) off[V_] = E_;
}

__global__ void k_fill(const int* __restrict__ src, const int* __restrict__ dst,
                       const int* __restrict__ off, int* __restrict__ cursor,
                       int* __restrict__ csr) {
    int e = blockIdx.x * 256 + threadIdx.x;
    if (e < E_) {
        int c = dst[e];
        int p = atomicAdd(&cursor[c], 1);
        csr[off[c] + p] = src[e];
    }
}

// ---------------------------------------------------------------------------
// Weight split + small prep
// ---------------------------------------------------------------------------

__global__ void k_wsplit(const float* __restrict__ W, ushort* __restrict__ Whi,
                         ushort* __restrict__ Wlo) {
    int i = blockIdx.x * 256 + threadIdx.x;
    float w = W[i];
    ushort hi, lo; bsplit(w, hi, lo);
    Whi[i] = hi; Wlo[i] = lo;
}

// Wxyz[j] = {Win[j][0..2], 0} packed f32x4
__global__ void k_prep(const float* __restrict__ Win, float* __restrict__ Wxyz) {
    int j = threadIdx.x;   // 128
    f32x4 v = {Win[(size_t)j*(LAT_+3)+0], Win[(size_t)j*(LAT_+3)+1],
               Win[(size_t)j*(LAT_+3)+2], 0.f};
    *(f32x4*)(Wxyz + j*4) = v;
}

__global__ void k_latproj(const float* __restrict__ Win, const float* __restrict__ bin,
                          const float* __restrict__ latent, float* __restrict__ latproj) {
    int t = blockIdx.x * 128 + threadIdx.x;
    if (t >= B_ * H_) return;
    int b = t >> 7, j = t & 127;
    const float* wr = Win + (size_t)j * (LAT_ + 3) + 3;
    const float* lp = latent + (size_t)b * LAT_;
    float s = bin[j];
    for (int k = 0; k < LAT_; k++) s = fmaf(wr[k], lp[k], s);
    latproj[t] = s;
}

// ---------------------------------------------------------------------------
// k_big: rows >= V (batches 1..3, no edges) fully fused:
// x0 -> 3 MFMA layers -> output head.  512 thr = 8 waves; 64-row tile;
// wave owns one 16-col slab (8 W frags in regs).  Single 32KB LDS x-buffer
// ([2 planes][64 rows][256B], swizzled); epilogue rewrites it in place.
// __launch_bounds__(512,2): VGPR ceiling 256 -> NO SPILL (R3 lesson: (512,4)
// capped VGPR at 64 and spilled ~18MB/dispatch to scratch).
// ---------------------------------------------------------------------------

__global__ __launch_bounds__(512, 2) void k_big(
        const float* __restrict__ xyz, const float* __restrict__ latproj,
        const float* __restrict__ Wxyz,
        const ushort* __restrict__ Whi, const ushort* __restrict__ Wlo,
        const float* __restrict__ convb,
        const float* __restrict__ Wout, const float* __restrict__ bout,
        float* __restrict__ out) {
    __shared__ __align__(16) char smem[32768];
    const int tid = threadIdx.x;
    const int row0 = V_ + blockIdx.x * 64;
    const int lane = tid & 63;
    const int wid  = tid >> 6;
    const int l15  = lane & 15;
    const int kg   = lane >> 4;
    const int n0   = wid * 16;
    const int tr   = tid >> 4;          // 0..31
    const int c0   = (tid & 15) * 8;

    // ---- x0 ----
#pragma unroll
    for (int rep = 0; rep < 2; rep++) {
        int row = tr + rep * 32;
        int node = row0 + row;
        ushort hs[8], ls[8];
        if (node < N_) {
            int v = node % V_, b = node / V_;
            float xv0 = xyz[v*3+0], xv1 = xyz[v*3+1], xv2 = xyz[v*3+2];
#pragma unroll
            for (int i = 0; i < 8; i++) {
                int j = c0 + i;
                f32x4 wx = *(const f32x4*)(Wxyz + j*4);
                float s = latproj[b*H_ + j];
                s = fmaf(wx[0], xv0, s);
                s = fmaf(wx[1], xv1, s);
                s = fmaf(wx[2], xv2, s);
                s = fmaxf(s, 0.f);
                bsplit(s, hs[i], ls[i]);
            }
        } else {
#pragma unroll
            for (int i = 0; i < 8; i++) { hs[i] = 0; ls[i] = 0; }
        }
        int bo = (c0*2) ^ swzr(row);
        *(uint4*)(smem + row*256 + bo) = *(uint4*)hs;
        *(uint4*)(smem + 16384 + row*256 + bo) = *(uint4*)ls;
    }
    __syncthreads();

    for (int l = 0; l < L_; l++) {
        const ushort* Whp = Whi + (size_t)l*H_*H_;
        const ushort* Wlp = Wlo + (size_t)l*H_*H_;
        short8 wh[4], wl[4];
#pragma unroll
        for (int ks = 0; ks < 4; ks++) {
            const ushort* bh = Whp + (size_t)(n0 + l15)*H_ + ks*32 + kg*4;
            const ushort* bl = Wlp + (size_t)(n0 + l15)*H_ + ks*32 + kg*4;
            union { short8 v; uint2 u[2]; } uh, ul;
            uh.u[0] = *(const uint2*)bh;  uh.u[1] = *(const uint2*)(bh + 16);
            ul.u[0] = *(const uint2*)bl;  ul.u[1] = *(const uint2*)(bl + 16);
            wh[ks] = uh.v; wl[ks] = ul.v;
        }
        f32x4 acc[4];
#pragma unroll
        for (int mt = 0; mt < 4; mt++) acc[mt] = (f32x4){0.f,0.f,0.f,0.f};
#pragma unroll
        for (int mt = 0; mt < 4; mt++) {
            int row = mt*16 + l15;
            int sw = swzr(row);
            const char* rbh = smem + row*256;
            const char* rbl = smem + 16384 + row*256;
#pragma unroll
            for (int ks = 0; ks < 4; ks++) {
                int cc = ks*64 + kg*8;
                union { short8 v; uint2 u[2]; } ah, al;
                ah.u[0] = *(const uint2*)(rbh + (cc ^ sw));
                ah.u[1] = *(const uint2*)(rbh + ((cc+32) ^ sw));
                al.u[0] = *(const uint2*)(rbl + (cc ^ sw));
                al.u[1] = *(const uint2*)(rbl + ((cc+32) ^ sw));
                acc[mt] = __builtin_amdgcn_mfma_f32_16x16x32_bf16(ah.v, wh[ks], acc[mt], 0,0,0);
                acc[mt] = __builtin_amdgcn_mfma_f32_16x16x32_bf16(al.v, wh[ks], acc[mt], 0,0,0);
                acc[mt] = __builtin_amdgcn_mfma_f32_16x16x32_bf16(ah.v, wl[ks], acc[mt], 0,0,0);
            }
        }
        __syncthreads();          // all waves done READING x
        float bv = convb[l*H_ + n0 + l15];
        int bo = (n0 + l15) * 2;
#pragma unroll
        for (int mt = 0; mt < 4; mt++)
#pragma unroll
            for (int j = 0; j < 4; j++) {
                int row = mt*16 + kg*4 + j;
                int sw = swzr(row);
                float v = fmaxf(acc[mt][j] + bv, 0.f);
                ushort hi, lo; bsplit(v, hi, lo);
                *(ushort*)(smem + row*256 + (bo ^ sw)) = hi;
                *(ushort*)(smem + 16384 + row*256 + (bo ^ sw)) = lo;
            }
        __syncthreads();          // x' fully written
    }

    // ---- output head ----
    float wo0[8], wo1[8], wo2[8];
#pragma unroll
    for (int i = 0; i < 8; i++) {
        wo0[i] = Wout[0*H_ + c0 + i];
        wo1[i] = Wout[1*H_ + c0 + i];
        wo2[i] = Wout[2*H_ + c0 + i];
    }
#pragma unroll
    for (int rep = 0; rep < 2; rep++) {
        int row = tr + rep*32;
        int node = row0 + row;
        int bo = (c0*2) ^ swzr(row);
        uint4 uh = *(const uint4*)(smem + row*256 + bo);
        uint4 ul = *(const uint4*)(smem + 16384 + row*256 + bo);
        const ushort* hp = (const ushort*)&uh;
        const ushort* lp = (const ushort*)&ul;
        float p0 = 0.f, p1 = 0.f, p2 = 0.f;
#pragma unroll
        for (int i = 0; i < 8; i++) {
            float xv = bjoin(hp[i], lp[i]);
            p0 = fmaf(xv, wo0[i], p0);
            p1 = fmaf(xv, wo1[i], p1);
            p2 = fmaf(xv, wo2[i], p2);
        }
#pragma unroll
        for (int m = 1; m < 16; m <<= 1) {
            p0 += __shfl_xor(p0, m);
            p1 += __shfl_xor(p1, m);
            p2 += __shfl_xor(p2, m);
        }
        if ((tid & 15) == 0 && node < N_) {
            out[(size_t)node*3 + 0] = p0 + bout[0];
            out[(size_t)node*3 + 1] = p1 + bout[1];
            out[(size_t)node*3 + 2] = p2 + bout[2];
        }
    }
}

// ---------------------------------------------------------------------------
// k_lay0: batch-0 GEMM h = x @ W^T, rows < V.  Same shape as k_big's layer:
// 512 thr, 64-row tile, 8 waves x 16-col slab, (512,2) no-spill.
// MODE 0: x0 computed in-kernel.  MODE 1: stage xh/xl from global.
// Epilogue: f32 h to global (no LDS bounce; 64B/row segments).
// ---------------------------------------------------------------------------

template<int MODE>
__global__ __launch_bounds__(512, 2) void k_lay0(
        const ushort* __restrict__ xh, const ushort* __restrict__ xl,
        const float* __restrict__ xyz, const float* __restrict__ latproj,
        const float* __restrict__ Wxyz,
        const ushort* __restrict__ Whp, const ushort* __restrict__ Wlp,
        float* __restrict__ h) {
    __shared__ __align__(16) char smem[32768];
    const int tid = threadIdx.x;
    const int row0 = blockIdx.x * 64;
    const int lane = tid & 63;
    const int wid  = tid >> 6;
    const int l15  = lane & 15;
    const int kg   = lane >> 4;
    const int n0   = wid * 16;
    const int tr   = tid >> 4;
    const int c0   = (tid & 15) * 8;

    if (MODE == 0) {
#pragma unroll
        for (int rep = 0; rep < 2; rep++) {
            int row = tr + rep * 32;
            int v = row0 + row;
            ushort hs[8], ls[8];
            if (v < V_) {
                float xv0 = xyz[v*3+0], xv1 = xyz[v*3+1], xv2 = xyz[v*3+2];
#pragma unroll
                for (int i = 0; i < 8; i++) {
                    int j = c0 + i;
                    f32x4 wx = *(const f32x4*)(Wxyz + j*4);
                    float s = latproj[j];                       // b = 0
                    s = fmaf(wx[0], xv0, s);
                    s = fmaf(wx[1], xv1, s);
                    s = fmaf(wx[2], xv2, s);
                    s = fmaxf(s, 0.f);
                    bsplit(s, hs[i], ls[i]);
                }
            } else {
#pragma unroll
                for (int i = 0; i < 8; i++) { hs[i] = 0; ls[i] = 0; }
            }
            int bo = (c0*2) ^ swzr(row);
            *(uint4*)(smem + row*256 + bo) = *(uint4*)hs;
            *(uint4*)(smem + 16384 + row*256 + bo) = *(uint4*)ls;
        }
    } else {
#pragma unroll
        for (int k = 0; k < 4; k++) {
            int chunk = tid + k*512;            // 2048 x 16B
            int p  = chunk >> 10;
            int r  = (chunk >> 4) & 63;
            int cb = (chunk & 15) * 16;
            int grow = row0 + r;
            uint4 g = {0u,0u,0u,0u};
            if (grow < V_)
                g = *(const uint4*)((const char*)((p ? xl : xh) + (size_t)grow*H_) + cb);
            *(uint4*)(smem + p*16384 + r*256 + (cb ^ swzr(r))) = g;
        }
    }
    __syncthreads();

    short8 wh[4], wl[4];
#pragma unroll
    for (int ks = 0; ks < 4; ks++) {
        const ushort* bh = Whp + (size_t)(n0 + l15)*H_ + ks*32 + kg*4;
        const ushort* bl = Wlp + (size_t)(n0 + l15)*H_ + ks*32 + kg*4;
        union { short8 v; uint2 u[2]; } uh, ul;
        uh.u[0] = *(const uint2*)bh;  uh.u[1] = *(const uint2*)(bh + 16);
        ul.u[0] = *(const uint2*)bl;  ul.u[1] = *(const uint2*)(bl + 16);
        wh[ks] = uh.v; wl[ks] = ul.v;
    }

    f32x4 acc[4];
#pragma unroll
    for (int mt = 0; mt < 4; mt++) acc[mt] = (f32x4){0.f,0.f,0.f,0.f};
#pragma unroll
    for (int mt = 0; mt < 4; mt++) {
        int row = mt*16 + l15;
        int sw = swzr(row);
        const char* rbh = smem + row*256;
        const char* rbl = smem + 16384 + row*256;
#pragma unroll
        for (int ks = 0; ks < 4; ks++) {
            int cc = ks*64 + kg*8;
            union { short8 v; uint2 u[2]; } ah, al;
            ah.u[0] = *(const uint2*)(rbh + (cc ^ sw));
            ah.u[1] = *(const uint2*)(rbh + ((cc+32) ^ sw));
            al.u[0] = *(const uint2*)(rbl + (cc ^ sw));
            al.u[1] = *(const uint2*)(rbl + ((cc+32) ^ sw));
            acc[mt] = __builtin_amdgcn_mfma_f32_16x16x32_bf16(ah.v, wh[ks], acc[mt], 0,0,0);
            acc[mt] = __builtin_amdgcn_mfma_f32_16x16x32_bf16(al.v, wh[ks], acc[mt], 0,0,0);
            acc[mt] = __builtin_amdgcn_mfma_f32_16x16x32_bf16(ah.v, wl[ks], acc[mt], 0,0,0);
        }
    }

#pragma unroll
    for (int mt = 0; mt < 4; mt++)
#pragma unroll
        for (int j = 0; j < 4; j++) {
            int grow = row0 + mt*16 + kg*4 + j;
            if (grow < V_) h[(size_t)grow*H_ + n0 + l15] = acc[mt][j];
        }
}

// ---------------------------------------------------------------------------
// Aggregation (batch-0).  One wave per node; lane-parallel CSR prefetch.
// ---------------------------------------------------------------------------

template<bool FINAL>
__global__ __launch_bounds__(256) void k_agg0(const float* __restrict__ h,
                                              const float* __restrict__ dis,
                                              const int* __restrict__ off,
                                              const int* __restrict__ csr,
                                              const float* __restrict__ bias,
                                              ushort* __restrict__ xh_out,
                                              ushort* __restrict__ xl_out,
                                              const float* __restrict__ Wout,
                                              const float* __restrict__ bout,
                                              float* __restrict__ out) {
    int c = blockIdx.x * 4 + (threadIdx.x >> 6);
    int lane = threadIdx.x & 63;
    if (c >= V_) return;
    int beg = off[c], end = off[c + 1];
    int nu = end - beg;
    int   myu  = (lane < nu) ? csr[beg + lane] : 0;
    float mywu = (lane < nu) ? dis[myu] : 0.f;
    float a0 = 0.f, a1 = 0.f;
    int nn = nu < 64 ? nu : 64;
    for (int i = 0; i < nn; i++) {
        int u = __shfl(myu, i);
        float wu = __shfl(mywu, i);
        const float* hu = h + (size_t)u * 128;
        a0 = fmaf(wu, hu[lane],      a0);
        a1 = fmaf(wu, hu[lane + 64], a1);
    }
    for (int i = beg + 64; i < end; i++) {
        int u = csr[i];
        float wu = dis[u];
        const float* hu = h + (size_t)u * 128;
        a0 = fmaf(wu, hu[lane],      a0);
        a1 = fmaf(wu, hu[lane + 64], a1);
    }
    float dc = dis[c];
    const float* hr = h + (size_t)c * 128;
    float s0 = fmaxf(dc * (float)B_ * a0 + dc * dc * hr[lane]      + bias[lane],      0.f);
    float s1 = fmaxf(dc * (float)B_ * a1 + dc * dc * hr[lane + 64] + bias[lane + 64], 0.f);
    if (FINAL) {
        float p0 = s0 * Wout[0*H_ + lane] + s1 * Wout[0*H_ + 64 + lane];
        float p1 = s0 * Wout[1*H_ + lane] + s1 * Wout[1*H_ + 64 + lane];
        float p2 = s0 * Wout[2*H_ + lane] + s1 * Wout[2*H_ + 64 + lane];
#pragma unroll
        for (int d = 32; d; d >>= 1) {
            p0 += __shfl_down(p0, d);
            p1 += __shfl_down(p1, d);
            p2 += __shfl_down(p2, d);
        }
        if (lane == 0) {
            out[(size_t)c*3 + 0] = p0 + bout[0];
            out[(size_t)c*3 + 1] = p1 + bout[1];
            out[(size_t)c*3 + 2] = p2 + bout[2];
        }
    } else {
        ushort h0, l0, h1, l1;
        bsplit(s0, h0, l0);
        bsplit(s1, h1, l1);
        xh_out[(size_t)c*128 + lane]      = h0;
        xl_out[(size_t)c*128 + lane]      = l0;
        xh_out[(size_t)c*128 + lane + 64] = h1;
        xl_out[(size_t)c*128 + lane + 64] = l1;
    }
}

// ---------------------------------------------------------------------------

extern "C" void kernel_launch(void* const* d_in, const int* in_sizes, int n_in,
                              void* d_out, int out_size, void* d_ws, size_t ws_size,
                              hipStream_t stream) {
    const float* xyz    = (const float*)d_in[0];
    const float* latent = (const float*)d_in[1];
    const int*   ei     = (const int*)d_in[2];
    const float* Win    = (const float*)d_in[3];
    const float* bin    = (const float*)d_in[4];
    const float* convW  = (const float*)d_in[5];
    const float* convb  = (const float*)d_in[6];
    const float* Wout   = (const float*)d_in[7];
    const float* bout   = (const float*)d_in[8];
    float* out = (float*)d_out;

    char* w = (char*)d_ws;
    auto carve = [&](size_t bytes) {
        char* p = w;
        w += (bytes + 255) & ~(size_t)255;
        return p;
    };
    ushort* xh      = (ushort*)carve((size_t)V_ * H_ * 2);
    ushort* xl      = (ushort*)carve((size_t)V_ * H_ * 2);
    float*  h       = (float*)carve((size_t)V_ * H_ * 4);
    ushort* Whi     = (ushort*)carve((size_t)L_ * H_ * H_ * 2);
    ushort* Wlo     = (ushort*)carve((size_t)L_ * H_ * H_ * 2);
    float*  dis     = (float*)carve((size_t)V_ * 4);
    float*  latproj = (float*)carve((size_t)B_ * H_ * 4);
    float*  Wxyz    = (float*)carve((size_t)H_ * 4 * 4);
    int*    deg     = (int*)carve((size_t)V_ * 4);
    int*    off     = (int*)carve((size_t)(V_ + 1) * 4);
    int*    cursor  = (int*)carve((size_t)V_ * 4);
    int*    csr     = (int*)carve((size_t)E_ * 4);
    int*    part    = (int*)carve((size_t)SCAN_G * 4);
    (void)ws_size; (void)in_sizes; (void)n_in; (void)out_size;

    const int* src = ei;
    const int* dst = ei + E_;

    k_zero<<<(V_ + 255) / 256, 256, 0, stream>>>(deg, cursor);
    k_deg<<<(E_ + 255) / 256, 256, 0, stream>>>(dst, deg);
    k_scan1<<<SCAN_G, SCAN_B, 0, stream>>>(deg, off, dis, part);
    k_scan2<<<1, 128, 0, stream>>>(part);
    k_scan3<<<SCAN_G, SCAN_B, 0, stream>>>(off, part);
    k_fill<<<(E_ + 255) / 256, 256, 0, stream>>>(src, dst, off, cursor, csr);

    k_wsplit<<<(L_ * H_ * H_) / 256, 256, 0, stream>>>(convW, Whi, Wlo);
    k_prep<<<1, 128, 0, stream>>>(Win, Wxyz);
    k_latproj<<<4, 128, 0, stream>>>(Win, bin, latent, latproj);

    // batches 1..3: fully fused (no graph)
    k_big<<<(N_ - V_ + 63) / 64, 512, 0, stream>>>(xyz, latproj, Wxyz, Whi, Wlo,
                                                   convb, Wout, bout, out);

    // batch 0 chain
    const int GB0 = (V_ + 63) / 64;
    k_lay0<0><<<GB0, 512, 0, stream>>>(nullptr, nullptr, xyz, latproj, Wxyz,
                                       Whi, Wlo, h);
    k_agg0<false><<<(V_ + 3) / 4, 256, 0, stream>>>(h, dis, off, csr, convb,
                                                    xh, xl, nullptr, nullptr, nullptr);
    k_lay0<1><<<GB0, 512, 0, stream>>>(xh, xl, nullptr, nullptr, nullptr,
                                       Whi + (size_t)1*H_*H_, Wlo + (size_t)1*H_*H_, h);
    k_agg0<false><<<(V_ + 3) / 4, 256, 0, stream>>>(h, dis, off, csr, convb + 1*H_,
                                                    xh, xl, nullptr, nullptr, nullptr);
    k_lay0<1><<<GB0, 512, 0, stream>>>(xh, xl, nullptr, nullptr, nullptr,
                                       Whi + (size_t)2*H_*H_, Wlo + (size_t)2*H_*H_, h);
    k_agg0<true><<<(V_ + 3) / 4, 256, 0, stream>>>(h, dis, off, csr, convb + 2*H_,
                                                   nullptr, nullptr, Wout, bout, out);
}